// Round 9
// baseline (2656.537 us; speedup 1.0000x reference)
//
#include <hip/hip_runtime.h>
#include <hip/hip_fp16.h>
#include <math.h>

#define C_DIM 64
#define K_DIM 27
#define NPB   192   // nodes per bucket; LDS acc = 192*65*4 = 49,920 B < 64 KB

// ===================== shared helpers =====================

// Zero via memory-side atomics (plain-store zeroing raced in R3; atomicExch
// proven safe R4-R8).
__global__ __launch_bounds__(256) void zero_exch_kernel(
    unsigned long long* __restrict__ p, size_t nwords)
{
    const size_t stride = (size_t)gridDim.x * blockDim.x;
    for (size_t i = (size_t)blockIdx.x * blockDim.x + threadIdx.x; i < nwords; i += stride)
        atomicExch(&p[i], 0ull);
}

__global__ __launch_bounds__(256) void zero_cursor_kernel(
    unsigned int* __restrict__ c, int nb)
{
    const int i = blockIdx.x * 256 + threadIdx.x;
    if (i < nb) atomicExch(&c[i], 0u);
}

// ===================== bin -> accumulate path =====================
// Entry (h,k) -> bucket b = n/NPB. Bucket storage: payload = 32 u32 (64ch f16
// pairs), nodeArr = node id, cursor = per-bucket append count.

__global__ __launch_bounds__(256) void bin_kernel(
    const float* __restrict__ data_in,   // [C][K][H]
    const int* __restrict__ neigh,       // [H][K]
    unsigned int* __restrict__ payload,  // [NB*cap*32]
    unsigned int* __restrict__ nodeArr,  // [NB*cap]
    unsigned int* __restrict__ cursor,   // [NB]
    int H, int N, int cap, int hBase, int hEnd)
{
    __shared__ float tile[64][65];       // [h_local][c]; 65%32==1 -> conflict-free
    __shared__ unsigned int gsh[64];     // global slot index, ~0 = skip

    const int k    = blockIdx.x;         // k fastest: neigh rows L2-shared
    const int h0   = hBase + blockIdx.y * 64;
    const int tid  = threadIdx.x;
    const int lane = tid & 63;
    const int wid  = tid >> 6;
    const int rem  = min(64, hEnd - h0);

    // phase 0: reserve slots
    if (tid < 64) {
        unsigned int g = 0xFFFFFFFFu;
        if (tid < rem) {
            const int n = neigh[(size_t)(h0 + tid) * K_DIM + k];
            if (n >= 0 && n < N) {
                const int b = n / NPB;
                const unsigned int slot = atomicAdd(&cursor[b], 1u);
                if (slot < (unsigned int)cap) {
                    g = (unsigned int)b * (unsigned int)cap + slot;
                    nodeArr[g] = (unsigned int)n;
                }
            }
        }
        gsh[tid] = g;
    }

    // phase 1: coalesced nt load, transpose into LDS
    if (lane < rem) {
        const size_t base = (size_t)k * H + (size_t)h0 + lane;
        const size_t cstride = (size_t)K_DIM * H;
        #pragma unroll
        for (int i = 0; i < 16; ++i) {
            const int c = wid * 16 + i;
            tile[lane][c] = __builtin_nontemporal_load(&data_in[(size_t)c * cstride + base]);
        }
    }
    __syncthreads();

    // phase 2: 2 entries per wave-iteration; lane = 32*sub + j
    const int sub = lane >> 5;
    const int j   = lane & 31;
    #pragma unroll
    for (int it = 0; it < 8; ++it) {
        const int hl = wid * 16 + it * 2 + sub;
        const unsigned int g = gsh[hl];
        if (g != 0xFFFFFFFFu) {
            const __half2 v = __floats2half2_rn(tile[hl][2 * j + 0], tile[hl][2 * j + 1]);
            payload[(size_t)g * 32 + j] = __builtin_bit_cast(unsigned int, v); // full-line WC
        }
    }
}

__global__ __launch_bounds__(256) void accum_kernel(
    const unsigned int* __restrict__ payload,
    const unsigned int* __restrict__ nodeArr,
    const unsigned int* __restrict__ cursor,
    float* __restrict__ out,             // [64][N]
    int N, int cap, int accumulate)
{
    __shared__ float acc[NPB][65];       // (nl+c)%32 banking -> conflict-free

    const int b   = blockIdx.x;
    const int n0  = b * NPB;
    const int tid = threadIdx.x;
    const int lane = tid & 63;
    const int wid  = tid >> 6;

    for (int i = tid; i < NPB * 65; i += 256) ((float*)acc)[i] = 0.f;
    __syncthreads();

    const int cnt = min((int)cursor[b], cap);
    const int sub = lane >> 5;
    const int j   = lane & 31;
    for (int e = wid * 2 + sub; e < cnt; e += 8) {
        const size_t g  = (size_t)b * cap + e;
        const int    nl = (int)nodeArr[g] - n0;            // broadcast load
        const unsigned int raw = payload[g * 32 + j];      // coalesced 128B/entry
        const __half2 v = __builtin_bit_cast(__half2, raw);
        atomicAdd(&acc[nl][2 * j + 0], __low2float(v));    // ds_add_f32
        atomicAdd(&acc[nl][2 * j + 1], __high2float(v));
    }
    __syncthreads();

    const int nrem = min(NPB, N - n0);
    #pragma unroll
    for (int i = 0; i < 16; ++i) {
        const int c = wid * 16 + i;
        #pragma unroll
        for (int g2 = 0; g2 < NPB / 64; ++g2) {
            const int nl = g2 * 64 + lane;
            if (nl < nrem) {
                const size_t o = (size_t)c * N + (size_t)(n0 + nl);
                float val = acc[nl][c];
                if (accumulate) val += out[o];
                out[o] = val;
            }
        }
    }
}

// ===================== R8 fallback path (proven 441us) =====================

__global__ __launch_bounds__(256) void scatter_kernel(
    const float* __restrict__ data_in,
    const int* __restrict__ neigh,
    __half* __restrict__ acc,            // [N][64]
    int H, int N)
{
    __shared__ float tile[64][65];
    __shared__ int nsh[64];

    const int k    = blockIdx.x;
    const int h0   = blockIdx.y * 64;
    const int tid  = threadIdx.x;
    const int lane = tid & 63;
    const int wid  = tid >> 6;
    const int rem  = min(64, H - h0);

    if (tid < 64) {
        int n = -1;
        if (tid < rem) {
            n = neigh[(size_t)(h0 + tid) * K_DIM + k];
            if (n < 0 || n >= N) n = -1;
        }
        nsh[tid] = n;
    }
    if (lane < rem) {
        const size_t base = (size_t)k * H + (size_t)h0 + lane;
        const size_t cstride = (size_t)K_DIM * H;
        #pragma unroll
        for (int i = 0; i < 16; ++i) {
            const int c = wid * 16 + i;
            tile[lane][c] = __builtin_nontemporal_load(&data_in[(size_t)c * cstride + base]);
        }
    }
    __syncthreads();

    const int sub = lane >> 5;
    const int j   = lane & 31;
    #pragma unroll
    for (int it = 0; it < 8; ++it) {
        const int hl = wid * 16 + it * 2 + sub;
        const int n  = (hl < rem) ? nsh[hl] : -1;
        if (n >= 0) {
            const __half2 v = __floats2half2_rn(tile[hl][2 * j + 0], tile[hl][2 * j + 1]);
            unsafeAtomicAdd((__half2*)&acc[(size_t)n * 64 + 2 * j], v);
        }
    }
}

__global__ __launch_bounds__(256) void finalize_kernel(
    const __half* __restrict__ acc,
    float* __restrict__ out,
    int N)
{
    __shared__ float tile[64][65];

    const int n0   = blockIdx.x * 64;
    const int tid  = threadIdx.x;
    const int lane = tid & 63;
    const int wid  = tid >> 6;
    const int rem  = min(64, N - n0);

    #pragma unroll
    for (int r = 0; r < 8; ++r) {
        const int idx = r * 256 + tid;
        const int nl  = idx >> 5;
        const int j   = idx & 31;
        if (nl < rem) {
            const unsigned int raw = __builtin_nontemporal_load(
                (const unsigned int*)&acc[(size_t)(n0 + nl) * 64 + 2 * j]);
            const __half2 v = __builtin_bit_cast(__half2, raw);
            tile[2 * j + 0][nl] = __low2float(v);
            tile[2 * j + 1][nl] = __high2float(v);
        }
    }
    __syncthreads();

    if (lane < rem) {
        #pragma unroll
        for (int i = 0; i < 16; ++i) {
            const int c = wid * 16 + i;
            out[(size_t)c * N + (size_t)n0 + lane] = tile[c][lane];
        }
    }
}

__global__ void naive_scatter(
    const float* __restrict__ data_in,
    const int* __restrict__ neigh,
    float* __restrict__ out,
    int H, int N)
{
    const size_t total = (size_t)C_DIM * K_DIM * H;
    const size_t KH = (size_t)K_DIM * H;
    for (size_t t = (size_t)blockIdx.x * blockDim.x + threadIdx.x;
         t < total;
         t += (size_t)gridDim.x * blockDim.x) {
        const size_t c = t / KH;
        const size_t r = t - c * KH;
        const int k = (int)(r / H);
        const int h = (int)(r - (size_t)k * H);
        const int n = neigh[(size_t)h * K_DIM + k];
        if (n >= 0 && n < N) atomicAdd(&out[c * N + n], data_in[t]);
    }
}

// ===================== launch =====================

extern "C" void kernel_launch(void* const* d_in, const int* in_sizes, int n_in,
                              void* d_out, int out_size, void* d_ws, size_t ws_size,
                              hipStream_t stream) {
    const float* data_in = (const float*)d_in[0];
    const int*   neigh   = (const int*)d_in[1];
    float*       out     = (float*)d_out;

    const int H = in_sizes[1] / K_DIM;     // 150000
    const int N = out_size / C_DIM;        // 150000
    const int NB = (N + NPB - 1) / NPB;    // 782

    // ---- try bin->accumulate path: pick smallest pass count that fits ws
    const double entries = (double)H * (double)K_DIM;
    int P = 0;
    long long cap = 0;
    const size_t fixedBytes = (size_t)NB * 4 + 512;
    if (ws_size > fixedBytes + (1u << 20)) {
        const long long capAvail = (long long)((ws_size - fixedBytes) / ((size_t)NB * 132));
        const int cands[3] = {1, 2, 4};
        for (int ci = 0; ci < 3; ++ci) {
            const int p = cands[ci];
            const double mean = entries / p / NB;
            const long long need = (long long)(mean + 6.0 * sqrt(mean) + 16.0);
            if (capAvail >= need) {
                P = p;
                cap = capAvail < 4 * need ? capAvail : 4 * need;
                break;
            }
        }
    }

    if (P > 0) {
        unsigned int* payload = (unsigned int*)d_ws;                    // NB*cap*32 u32
        unsigned int* nodeArr = payload + (size_t)NB * cap * 32;        // NB*cap
        unsigned int* cursor  = nodeArr + (size_t)NB * cap;             // NB

        const int Hchunk = (((H + P - 1) / P) + 63) & ~63;              // 64-aligned
        for (int p = 0; p < P; ++p) {
            const int hBase = p * Hchunk;
            if (hBase >= H) break;
            const int hCnt = min(Hchunk, H - hBase);

            zero_cursor_kernel<<<(NB + 255) / 256, 256, 0, stream>>>(cursor, NB);

            dim3 g1(K_DIM, (hCnt + 63) / 64);
            bin_kernel<<<g1, 256, 0, stream>>>(data_in, neigh, payload, nodeArr,
                                               cursor, H, N, (int)cap,
                                               hBase, hBase + hCnt);

            accum_kernel<<<NB, 256, 0, stream>>>(payload, nodeArr, cursor, out,
                                                 N, (int)cap, p > 0 ? 1 : 0);
        }
        return;
    }

    // ---- R8 fallback: packed-f16 atomic scatter
    const size_t accBytes = (size_t)N * 64 * sizeof(__half);
    if (ws_size >= accBytes) {
        __half* acc = (__half*)d_ws;
        zero_exch_kernel<<<2048, 256, 0, stream>>>((unsigned long long*)d_ws, accBytes / 8);
        dim3 grid(K_DIM, (H + 63) / 64);
        scatter_kernel<<<grid, 256, 0, stream>>>(data_in, neigh, acc, H, N);
        finalize_kernel<<<(N + 63) / 64, 256, 0, stream>>>(acc, out, N);
    } else {
        (void)hipMemsetAsync(out, 0, (size_t)out_size * sizeof(float), stream);
        naive_scatter<<<2048, 256, 0, stream>>>(data_in, neigh, out, H, N);
    }
}

// Round 10
// 441.249 us; speedup vs baseline: 6.0205x; 6.0205x over previous
//
#include <hip/hip_runtime.h>
#include <hip/hip_fp16.h>

#define C_DIM 64
#define K_DIM 27

// R10 = revert to R8 (proven 441 us). Packed-f16 atomic accumulation:
//   acc: __half[N][64]; one global_atomic_pk_add_f16 adds 2 channels.
// Ceiling argument (R1/R4/R6/R8/R9 measurements):
//   - atomic RMW wall: ~19.4G line-visits/s, 64B write-through per visit
//     (WRITE_SIZE == visits x 64B every round). 128B/entry f16 payload
//     = 8.1M visits -> ~410-420us scatter; R8 measured ~410.
//   - total traffic 1.04GB read + 1.01GB RMW write-through + 158MB
//     finalize = 2.2GB in 441us = ~5TB/s effective (~80% of 6.3TB/s).
//   - the bin->accumulate alternative (R9) prices at >=400us ideal and
//     measured 2656us: no strategy eliminates the intermediate traffic.

// Zero the workspace via memory-side atomics (same coherence path as the
// scatter's atomics). Plain-store zeroing raced in R3; atomicExch is
// proven safe (R4-R8).
__global__ __launch_bounds__(256) void zero_exch_kernel(
    unsigned long long* __restrict__ p, size_t nwords)
{
    const size_t stride = (size_t)gridDim.x * blockDim.x;
    for (size_t i = (size_t)blockIdx.x * blockDim.x + threadIdx.x; i < nwords; i += stride)
        atomicExch(&p[i], 0ull);
}

__global__ __launch_bounds__(256) void scatter_kernel(
    const float* __restrict__ data_in,   // [C][K][H]
    const int* __restrict__ neigh,       // [H][K]
    __half* __restrict__ acc,            // [N][64]
    int H, int N)
{
    __shared__ float tile[64][65];   // [h_local][c]; 65 % 32 == 1 -> 2-way max (free)
    __shared__ int nsh[64];

    const int k    = blockIdx.x;         // k fastest: 27 same-h0 blocks adjacent
    const int h0   = blockIdx.y * 64;    //   -> neigh row reads L2/L3-shared
    const int tid  = threadIdx.x;
    const int lane = tid & 63;
    const int wid  = tid >> 6;       // 0..3
    const int rem  = min(64, H - h0);

    // ---- phase 0: neighbor ids into LDS
    if (tid < 64) {
        int n = -1;
        if (tid < rem) {
            n = neigh[(size_t)(h0 + tid) * K_DIM + k];
            if (n < 0 || n >= N) n = -1;
        }
        nsh[tid] = n;
    }

    // ---- phase 1: coalesced nontemporal load (streamed once; keep L3 for acc)
    if (lane < rem) {
        const size_t base = (size_t)k * H + (size_t)h0 + lane;
        const size_t cstride = (size_t)K_DIM * H;
        #pragma unroll
        for (int i = 0; i < 16; ++i) {
            const int c = wid * 16 + i;
            tile[lane][c] = __builtin_nontemporal_load(&data_in[(size_t)c * cstride + base]);
        }
    }
    __syncthreads();

    // ---- phase 2: wave wid owns entries hl = wid*16..wid*16+15, 2 per iter.
    // lane = 32*sub + j : sub selects entry within pair, j = half2 slot (0..31).
    const int sub = lane >> 5;
    const int j   = lane & 31;
    #pragma unroll
    for (int it = 0; it < 8; ++it) {
        const int hl = wid * 16 + it * 2 + sub;
        const int n  = (hl < rem) ? nsh[hl] : -1;
        if (n >= 0) {
            const float x0 = tile[hl][2 * j + 0];
            const float x1 = tile[hl][2 * j + 1];
            const __half2 v = __floats2half2_rn(x0, x1);
            // global_atomic_pk_add_f16, fire-and-forget
            unsafeAtomicAdd((__half2*)&acc[(size_t)n * 64 + 2 * j], v);
        }
    }
}

// acc [N][64] f16 -> out [64][N] f32 (convert + transpose).
__global__ __launch_bounds__(256) void finalize_kernel(
    const __half* __restrict__ acc,
    float* __restrict__ out,
    int N)
{
    __shared__ float tile[64][65];   // [c][n_local]

    const int n0   = blockIdx.x * 64;
    const int tid  = threadIdx.x;
    const int lane = tid & 63;
    const int wid  = tid >> 6;
    const int rem  = min(64, N - n0);

    // 2048 half2 per tile; 8 per thread, coalesced.
    #pragma unroll
    for (int r = 0; r < 8; ++r) {
        const int idx = r * 256 + tid;      // 0..2047
        const int nl  = idx >> 5;
        const int j   = idx & 31;
        if (nl < rem) {
            const unsigned int raw = __builtin_nontemporal_load(
                (const unsigned int*)&acc[(size_t)(n0 + nl) * 64 + 2 * j]);
            const __half2 v = __builtin_bit_cast(__half2, raw);
            tile[2 * j + 0][nl] = __low2float(v);
            tile[2 * j + 1][nl] = __high2float(v);
        }
    }
    __syncthreads();

    if (lane < rem) {
        #pragma unroll
        for (int i = 0; i < 16; ++i) {
            const int c = wid * 16 + i;
            out[(size_t)c * N + (size_t)n0 + lane] = tile[c][lane];
        }
    }
}

// Fallback if workspace is too small: direct f32 atomics into out [C][N].
__global__ void naive_scatter(
    const float* __restrict__ data_in,
    const int* __restrict__ neigh,
    float* __restrict__ out,
    int H, int N)
{
    const size_t total = (size_t)C_DIM * K_DIM * H;
    const size_t KH = (size_t)K_DIM * H;
    for (size_t t = (size_t)blockIdx.x * blockDim.x + threadIdx.x;
         t < total;
         t += (size_t)gridDim.x * blockDim.x) {
        const size_t c = t / KH;
        const size_t r = t - c * KH;
        const int k = (int)(r / H);
        const int h = (int)(r - (size_t)k * H);
        const int n = neigh[(size_t)h * K_DIM + k];
        if (n >= 0 && n < N) {
            atomicAdd(&out[c * N + n], data_in[t]);
        }
    }
}

extern "C" void kernel_launch(void* const* d_in, const int* in_sizes, int n_in,
                              void* d_out, int out_size, void* d_ws, size_t ws_size,
                              hipStream_t stream) {
    const float* data_in = (const float*)d_in[0];
    const int*   neigh   = (const int*)d_in[1];
    float*       out     = (float*)d_out;

    const int H = in_sizes[1] / K_DIM;     // 150000
    const int N = out_size / C_DIM;        // 150000

    const size_t accBytes = (size_t)N * 64 * sizeof(__half);   // 19.2 MB

    if (ws_size >= accBytes) {
        __half* acc = (__half*)d_ws;

        const size_t nwords = accBytes / 8;
        zero_exch_kernel<<<2048, 256, 0, stream>>>((unsigned long long*)d_ws, nwords);

        dim3 grid(K_DIM, (H + 63) / 64);
        scatter_kernel<<<grid, 256, 0, stream>>>(data_in, neigh, acc, H, N);

        finalize_kernel<<<(N + 63) / 64, 256, 0, stream>>>(acc, out, N);
    } else {
        (void)hipMemsetAsync(out, 0, (size_t)out_size * sizeof(float), stream);
        naive_scatter<<<2048, 256, 0, stream>>>(data_in, neigh, out, H, N);
    }
}